// Round 1
// 1267.223 us; speedup vs baseline: 1.0359x; 1.0359x over previous
//
#include <hip/hip_runtime.h>
#include <hip/hip_bf16.h>
#include <math.h>

#define H_DIM 2048
#define F_DIM 768
#define E_NUM 32
#define TOPK 4
#define SF_DIM 5632
#define T_NUM 2048
#define P_MAX (T_NUM * TOPK)
#define KSPLIT 4  // split-K for shared down-proj: 256 -> 1024 blocks (1 -> 4 blocks/CU)

typedef __attribute__((ext_vector_type(8))) short short8v;
typedef __attribute__((ext_vector_type(4))) float f4;
typedef unsigned short u16;

__device__ __forceinline__ u16 f2b(float f) {
  unsigned int u = __float_as_uint(f);
  u += 0x7FFFu + ((u >> 16) & 1u);
  return (u16)(u >> 16);
}

__device__ __forceinline__ f4 mfma16(short8v a, short8v b, f4 c) {
  return __builtin_amdgcn_mfma_f32_16x16x32_bf16(a, b, c, 0, 0, 0);
}

// async 16B global->LDS (wave-uniform base + lane*16 ordering)
__device__ __forceinline__ void gld16(const u16* g, u16* l) {
  __builtin_amdgcn_global_load_lds(
      (const __attribute__((address_space(1))) void*)g,
      (__attribute__((address_space(3))) void*)l, 16, 0, 0);
}

// ---------------------------------------------------------------------------
// Router: 1 block (64 threads) per token. fp32 logits/softmax/top-4.
// Outputs per-expert token lists + per-token slot map (for combine).
// ---------------------------------------------------------------------------
__global__ __launch_bounds__(64) void router_kernel(
    const float* __restrict__ x, const float* __restrict__ gate_w,
    const float* __restrict__ seg, int* __restrict__ cnt,
    int* __restrict__ toklist, int* __restrict__ slotE,
    int* __restrict__ slotPos, float* __restrict__ wt4,
    float* __restrict__ sigbuf) {
  const int t = blockIdx.x;
  const int l = threadIdx.x;
  const int e = l & 31;
  const int half = l >> 5;
  const float* xr = x + (size_t)t * H_DIM;

  float acc = 0.0f, aseg = 0.0f;
  const int h0 = half * (H_DIM / 2);
  for (int h = 0; h < H_DIM / 2; ++h) {
    float xv = xr[h0 + h];
    acc += xv * gate_w[(h0 + h) * E_NUM + e];
    aseg += xv * seg[h0 + h];
  }
  acc += __shfl_xor(acc, 32, 64);
  aseg += __shfl_xor(aseg, 32, 64);

  float m = acc;
#pragma unroll
  for (int mask = 16; mask >= 1; mask >>= 1) m = fmaxf(m, __shfl_xor(m, mask, 64));
  float p = expf(acc - m);
  float s = p;
#pragma unroll
  for (int mask = 16; mask >= 1; mask >>= 1) s += __shfl_xor(s, mask, 64);
  p /= s;

  float pv = p;
  int ids[TOPK];
  float wv[TOPK];
  float wsum = 0.0f;
#pragma unroll
  for (int k = 0; k < TOPK; ++k) {
    float mv = pv;
    int mi = e;
#pragma unroll
    for (int mask = 16; mask >= 1; mask >>= 1) {
      float ov = __shfl_xor(mv, mask, 64);
      int oi = __shfl_xor(mi, mask, 64);
      if (ov > mv || (ov == mv && oi < mi)) { mv = ov; mi = oi; }
    }
    ids[k] = mi;
    wv[k] = mv;
    wsum += mv;
    if (e == mi) pv = -1.0f;
  }

  if (l < TOPK) {
    int id = ids[l];
    float w = wv[l] / wsum;
    int pos = atomicAdd(&cnt[id], 1);
    toklist[id * T_NUM + pos] = t;
    slotE[t * TOPK + l] = id;
    slotPos[t * TOPK + l] = pos;
    wt4[t * TOPK + l] = w;
  }
  if (l == 0) sigbuf[t] = 1.0f / (1.0f + expf(-aseg));
}

// exclusive prefix over 32 counts
__global__ void offs_kernel(const int* __restrict__ cnt, int* __restrict__ offs) {
  if (threadIdx.x == 0) {
    int s = 0;
    for (int e = 0; e < E_NUM; ++e) { offs[e] = s; s += cnt[e]; }
  }
}

// x fp32 -> bf16 (row-major, no transpose). 8 elems/thread.
__global__ __launch_bounds__(256) void cvt_x(const float* __restrict__ in,
                                             u16* __restrict__ out) {
  int i = blockIdx.x * 256 + threadIdx.x;
  const float4* p = (const float4*)in + (size_t)i * 2;
  float4 a = p[0], b = p[1];
  short8v o;
  o[0] = (short)f2b(a.x); o[1] = (short)f2b(a.y);
  o[2] = (short)f2b(a.z); o[3] = (short)f2b(a.w);
  o[4] = (short)f2b(b.x); o[5] = (short)f2b(b.y);
  o[6] = (short)f2b(b.z); o[7] = (short)f2b(b.w);
  *(short8v*)(out + (size_t)i * 8) = o;
}

// fp32 [R][C] -> bf16 [C][R] (per-z matrix), 64x64 tiles via LDS
__global__ __launch_bounds__(256) void transpose_cvt(
    const float* __restrict__ in, u16* __restrict__ out, int R, int C) {
  in += (size_t)blockIdx.z * R * C;
  out += (size_t)blockIdx.z * R * C;
  const int r0 = blockIdx.y * 64;
  const int c0 = blockIdx.x * 64;
  __shared__ u16 tile[64][72];
  const int tid = threadIdx.x;
  const int tr = tid >> 2, tseg = tid & 3;
  const float* ip = in + (size_t)(r0 + tr) * C + c0 + tseg * 16;
#pragma unroll
  for (int j = 0; j < 4; ++j) {
    float4 v = *(const float4*)(ip + j * 4);
    u16* d = &tile[tr][tseg * 16 + j * 4];
    d[0] = f2b(v.x); d[1] = f2b(v.y); d[2] = f2b(v.z); d[3] = f2b(v.w);
  }
  __syncthreads();
  u16 tmp[16];
#pragma unroll
  for (int j = 0; j < 16; ++j) tmp[j] = tile[tseg * 16 + j][tr];
  u16* op = out + (size_t)(c0 + tr) * R + r0 + tseg * 16;
  *(short8v*)op = *(short8v*)&tmp[0];
  *(short8v*)(op + 8) = *(short8v*)&tmp[8];
}

// ---------------------------------------------------------------------------
// Fused gate+up GEMM: H = silu(A@Bg^T)*(A@Bu^T), bf16 out.
// BM=128, BN=64, BK=32. A rows gathered via ids[] (direct or toklist).
// Bg/Bu are B^T [N][K] bf16. LDS chunk-swizzle c=(s+(r>>1))&3 -> 2-way free.
// ---------------------------------------------------------------------------
__global__ __launch_bounds__(256) void gemm_gu(
    const u16* __restrict__ A, const u16* __restrict__ Bg,
    const u16* __restrict__ Bu, u16* __restrict__ Hout,
    int K, int N, int gather, const int* __restrict__ cnt,
    const int* __restrict__ toklist, const int* __restrict__ offs) {
  const int e = blockIdx.z;
  const int mtile = blockIdx.y;
  const int n0 = blockIdx.x * 64;
  int count = 1 << 30, obase = 0;
  if (gather) {
    count = cnt[e];
    if (mtile * 128 >= count) return;
    obase = offs[e];
    Bg += (size_t)e * N * K;
    Bu += (size_t)e * N * K;
  }

  __shared__ u16 As[128 * 32];
  __shared__ u16 Bgs[64 * 32];
  __shared__ u16 Bus[64 * 32];
  __shared__ int ids[128];

  const int tid = threadIdx.x;
  if (tid < 128) {
    int idx = mtile * 128 + tid;
    ids[tid] = gather ? toklist[e * T_NUM + min(idx, count - 1)] : idx;
  }
  __syncthreads();

  const int s = tid & 3, r0 = tid >> 2;
  const int cA0 = (s + (r0 >> 1)) & 3;
  const int cA1 = (s + ((r0 + 64) >> 1)) & 3;
  const u16* ap0 = A + (size_t)ids[r0] * K + cA0 * 8;
  const u16* ap1 = A + (size_t)ids[r0 + 64] * K + cA1 * 8;
  u16* al0 = As + tid * 8;
  u16* al1 = As + tid * 8 + 2048;
  const u16* bgp = Bg + (size_t)(n0 + r0) * K + cA0 * 8;
  const u16* bup = Bu + (size_t)(n0 + r0) * K + cA0 * 8;
  u16* bgl = Bgs + tid * 8;
  u16* bul = Bus + tid * 8;

  const int lane = tid & 63, w = tid >> 6;
  const int w0 = w & 1, w1 = w >> 1;
  const int ln = lane & 15, q = lane >> 4;

  int aoff[4], boff[2];
#pragma unroll
  for (int mt = 0; mt < 4; ++mt) {
    int r = w0 * 64 + mt * 16 + ln;
    aoff[mt] = r * 32 + ((q - (r >> 1)) & 3) * 8;
  }
#pragma unroll
  for (int nt = 0; nt < 2; ++nt) {
    int r = w1 * 32 + nt * 16 + ln;
    boff[nt] = r * 32 + ((q - (r >> 1)) & 3) * 8;
  }

  const f4 zero = {0.f, 0.f, 0.f, 0.f};
  f4 accg[4][2], accu[4][2];
#pragma unroll
  for (int mt = 0; mt < 4; ++mt)
#pragma unroll
    for (int nt = 0; nt < 2; ++nt) { accg[mt][nt] = zero; accu[mt][nt] = zero; }

  for (int k0 = 0; k0 < K; k0 += 32) {
    gld16(ap0 + k0, al0);
    gld16(ap1 + k0, al1);
    gld16(bgp + k0, bgl);
    gld16(bup + k0, bul);
    __syncthreads();
    short8v av[4], bgv[2], buv[2];
#pragma unroll
    for (int mt = 0; mt < 4; ++mt) av[mt] = *(const short8v*)&As[aoff[mt]];
#pragma unroll
    for (int nt = 0; nt < 2; ++nt) {
      bgv[nt] = *(const short8v*)&Bgs[boff[nt]];
      buv[nt] = *(const short8v*)&Bus[boff[nt]];
    }
#pragma unroll
    for (int mt = 0; mt < 4; ++mt)
#pragma unroll
      for (int nt = 0; nt < 2; ++nt) {
        accg[mt][nt] = mfma16(av[mt], bgv[nt], accg[mt][nt]);
        accu[mt][nt] = mfma16(av[mt], buv[nt], accu[mt][nt]);
      }
    __syncthreads();
  }

#pragma unroll
  for (int mt = 0; mt < 4; ++mt)
#pragma unroll
    for (int nt = 0; nt < 2; ++nt)
#pragma unroll
      for (int r = 0; r < 4; ++r) {
        int m = w0 * 64 + mt * 16 + 4 * q + r;
        int idx = mtile * 128 + m;
        if (idx < count) {
          int n = n0 + w1 * 32 + nt * 16 + ln;
          float g = accg[mt][nt][r], u = accu[mt][nt][r];
          float h = g / (1.0f + __expf(-g)) * u;
          Hout[(size_t)(obase + idx) * N + n] = f2b(h);
        }
      }
}

// ---------------------------------------------------------------------------
// Plain GEMM: D = A@Bt^T (fp32 out). BM=128, BN=128, BK=32.
// gather mode: A rows are a contiguous expert segment [offs[e], offs[e]+cnt).
// ---------------------------------------------------------------------------
__global__ __launch_bounds__(256) void gemm_dn(
    const u16* __restrict__ A, const u16* __restrict__ Bt,
    float* __restrict__ D, int K, int N, int gather,
    const int* __restrict__ cnt, const int* __restrict__ offs) {
  const int e = blockIdx.z;
  const int mtile = blockIdx.y;
  const int n0 = blockIdx.x * 128;
  int count = 1 << 30, obase = 0;
  if (gather) {
    count = cnt[e];
    if (mtile * 128 >= count) return;
    obase = offs[e];
    Bt += (size_t)e * N * K;
  }

  __shared__ u16 As[128 * 32];
  __shared__ u16 Bs[128 * 32];
  __shared__ int ids[128];

  const int tid = threadIdx.x;
  if (tid < 128) {
    int idx = mtile * 128 + tid;
    ids[tid] = gather ? (obase + min(idx, count - 1)) : idx;
  }
  __syncthreads();

  const int s = tid & 3, r0 = tid >> 2;
  const int cA0 = (s + (r0 >> 1)) & 3;
  const int cA1 = (s + ((r0 + 64) >> 1)) & 3;
  const u16* ap0 = A + (size_t)ids[r0] * K + cA0 * 8;
  const u16* ap1 = A + (size_t)ids[r0 + 64] * K + cA1 * 8;
  u16* al0 = As + tid * 8;
  u16* al1 = As + tid * 8 + 2048;
  const u16* bp0 = Bt + (size_t)(n0 + r0) * K + cA0 * 8;
  const u16* bp1 = Bt + (size_t)(n0 + r0 + 64) * K + cA1 * 8;
  u16* bl0 = Bs + tid * 8;
  u16* bl1 = Bs + tid * 8 + 2048;

  const int lane = tid & 63, w = tid >> 6;
  const int w0 = w & 1, w1 = w >> 1;
  const int ln = lane & 15, q = lane >> 4;

  int aoff[4], boff[4];
#pragma unroll
  for (int mt = 0; mt < 4; ++mt) {
    int r = w0 * 64 + mt * 16 + ln;
    aoff[mt] = r * 32 + ((q - (r >> 1)) & 3) * 8;
    int rb = w1 * 64 + mt * 16 + ln;
    boff[mt] = rb * 32 + ((q - (rb >> 1)) & 3) * 8;
  }

  const f4 zero = {0.f, 0.f, 0.f, 0.f};
  f4 acc[4][4];
#pragma unroll
  for (int mt = 0; mt < 4; ++mt)
#pragma unroll
    for (int nt = 0; nt < 4; ++nt) acc[mt][nt] = zero;

  for (int k0 = 0; k0 < K; k0 += 32) {
    gld16(ap0 + k0, al0);
    gld16(ap1 + k0, al1);
    gld16(bp0 + k0, bl0);
    gld16(bp1 + k0, bl1);
    __syncthreads();
    short8v av[4], bv[4];
#pragma unroll
    for (int i = 0; i < 4; ++i) {
      av[i] = *(const short8v*)&As[aoff[i]];
      bv[i] = *(const short8v*)&Bs[boff[i]];
    }
#pragma unroll
    for (int mt = 0; mt < 4; ++mt)
#pragma unroll
      for (int nt = 0; nt < 4; ++nt)
        acc[mt][nt] = mfma16(av[mt], bv[nt], acc[mt][nt]);
    __syncthreads();
  }

#pragma unroll
  for (int mt = 0; mt < 4; ++mt)
#pragma unroll
    for (int nt = 0; nt < 4; ++nt)
#pragma unroll
      for (int r = 0; r < 4; ++r) {
        int m = w0 * 64 + mt * 16 + 4 * q + r;
        int idx = mtile * 128 + m;
        if (idx < count) {
          int n = n0 + w1 * 64 + nt * 16 + ln;
          D[(size_t)(obase + idx) * N + n] = acc[mt][nt][r];
        }
      }
}

// ---------------------------------------------------------------------------
// Split-K GEMM for the shared down-proj: D_z = A[:, kz] @ Bt[:, kz]^T.
// Same 128x128 tile as gemm_dn (keeps 16-MFMA/K-step density) but grid z
// splits K into KSPLIT chunks -> 4x the blocks (1 -> 4 blocks/CU), which is
// what hides the global_load_lds barrier drain (m102: 1 blk/CU = 320 TF,
// 4 blk/CU = 833 TF). Partials summed (fp32, deterministic) in combine.
// ---------------------------------------------------------------------------
__global__ __launch_bounds__(256) void gemm_dn_split(
    const u16* __restrict__ A, const u16* __restrict__ Bt,
    float* __restrict__ D, int K, int N) {
  const int mtile = blockIdx.y;
  const int n0 = blockIdx.x * 128;
  const int kz = blockIdx.z;
  const int klen = K / KSPLIT;
  const int kbeg = kz * klen;
  D += (size_t)kz * T_NUM * N;  // partial-sum buffer for this K-chunk

  __shared__ u16 As[128 * 32];
  __shared__ u16 Bs[128 * 32];

  const int tid = threadIdx.x;
  const int s = tid & 3, r0 = tid >> 2;
  const int cA0 = (s + (r0 >> 1)) & 3;
  const int cA1 = (s + ((r0 + 64) >> 1)) & 3;
  const u16* ap0 = A + (size_t)(mtile * 128 + r0) * K + kbeg + cA0 * 8;
  const u16* ap1 = A + (size_t)(mtile * 128 + r0 + 64) * K + kbeg + cA1 * 8;
  u16* al0 = As + tid * 8;
  u16* al1 = As + tid * 8 + 2048;
  const u16* bp0 = Bt + (size_t)(n0 + r0) * K + kbeg + cA0 * 8;
  const u16* bp1 = Bt + (size_t)(n0 + r0 + 64) * K + kbeg + cA1 * 8;
  u16* bl0 = Bs + tid * 8;
  u16* bl1 = Bs + tid * 8 + 2048;

  const int lane = tid & 63, w = tid >> 6;
  const int w0 = w & 1, w1 = w >> 1;
  const int ln = lane & 15, q = lane >> 4;

  int aoff[4], boff[4];
#pragma unroll
  for (int mt = 0; mt < 4; ++mt) {
    int r = w0 * 64 + mt * 16 + ln;
    aoff[mt] = r * 32 + ((q - (r >> 1)) & 3) * 8;
    int rb = w1 * 64 + mt * 16 + ln;
    boff[mt] = rb * 32 + ((q - (rb >> 1)) & 3) * 8;
  }

  const f4 zero = {0.f, 0.f, 0.f, 0.f};
  f4 acc[4][4];
#pragma unroll
  for (int mt = 0; mt < 4; ++mt)
#pragma unroll
    for (int nt = 0; nt < 4; ++nt) acc[mt][nt] = zero;

  for (int k0 = 0; k0 < klen; k0 += 32) {
    gld16(ap0 + k0, al0);
    gld16(ap1 + k0, al1);
    gld16(bp0 + k0, bl0);
    gld16(bp1 + k0, bl1);
    __syncthreads();
    short8v av[4], bv[4];
#pragma unroll
    for (int i = 0; i < 4; ++i) {
      av[i] = *(const short8v*)&As[aoff[i]];
      bv[i] = *(const short8v*)&Bs[boff[i]];
    }
#pragma unroll
    for (int mt = 0; mt < 4; ++mt)
#pragma unroll
      for (int nt = 0; nt < 4; ++nt)
        acc[mt][nt] = mfma16(av[mt], bv[nt], acc[mt][nt]);
    __syncthreads();
  }

#pragma unroll
  for (int mt = 0; mt < 4; ++mt)
#pragma unroll
    for (int nt = 0; nt < 4; ++nt)
#pragma unroll
      for (int r = 0; r < 4; ++r) {
        int m = w0 * 64 + mt * 16 + 4 * q + r;
        int n = n0 + w1 * 64 + nt * 16 + ln;
        D[(size_t)(mtile * 128 + m) * N + n] = acc[mt][nt][r];
      }
}

// ---------------------------------------------------------------------------
// Final combine: out[t] = sig[t]*sum_z sharedD_z[t] + sum_k wt[t][k]*Dh[slot]
// ---------------------------------------------------------------------------
__global__ __launch_bounds__(256) void combine_kernel(
    const float* __restrict__ sD, const float* __restrict__ Dh,
    const float* __restrict__ sig, const float* __restrict__ wt4,
    const int* __restrict__ slotE, const int* __restrict__ slotPos,
    const int* __restrict__ offs, float* __restrict__ out) {
  const int t = blockIdx.x;
  const int c = threadIdx.x * 8;
  const float sg = sig[t];
  float o[8] = {0.f, 0.f, 0.f, 0.f, 0.f, 0.f, 0.f, 0.f};
#pragma unroll
  for (int z = 0; z < KSPLIT; ++z) {
    const float* sp = sD + ((size_t)z * T_NUM + t) * H_DIM + c;
    float4 a0 = *(const float4*)sp;
    float4 a1 = *(const float4*)(sp + 4);
    o[0] += a0.x; o[1] += a0.y; o[2] += a0.z; o[3] += a0.w;
    o[4] += a1.x; o[5] += a1.y; o[6] += a1.z; o[7] += a1.w;
  }
#pragma unroll
  for (int j = 0; j < 8; ++j) o[j] *= sg;
#pragma unroll
  for (int k = 0; k < TOPK; ++k) {
    int ee = slotE[t * TOPK + k];
    int pp = offs[ee] + slotPos[t * TOPK + k];
    float w = wt4[t * TOPK + k];
    const float* dp = Dh + (size_t)pp * H_DIM + c;
    float4 d0 = *(const float4*)dp;
    float4 d1 = *(const float4*)(dp + 4);
    o[0] += w * d0.x; o[1] += w * d0.y; o[2] += w * d0.z; o[3] += w * d0.w;
    o[4] += w * d1.x; o[5] += w * d1.y; o[6] += w * d1.z; o[7] += w * d1.w;
  }
  float* op = out + (size_t)t * H_DIM + c;
  float4 r0 = {o[0], o[1], o[2], o[3]};
  float4 r1 = {o[4], o[5], o[6], o[7]};
  *(float4*)op = r0;
  *(float4*)(op + 4) = r1;
}

// ---------------------------------------------------------------------------
extern "C" void kernel_launch(void* const* d_in, const int* in_sizes, int n_in,
                              void* d_out, int out_size, void* d_ws, size_t ws_size,
                              hipStream_t stream) {
  const float* x      = (const float*)d_in[0];
  const float* gate_w = (const float*)d_in[1];
  const float* wg     = (const float*)d_in[2];
  const float* wu     = (const float*)d_in[3];
  const float* wd     = (const float*)d_in[4];
  const float* sg     = (const float*)d_in[5];
  const float* su     = (const float*)d_in[6];
  const float* sd     = (const float*)d_in[7];
  const float* seg    = (const float*)d_in[8];
  float* out = (float*)d_out;

  char* p = (char*)d_ws;
  auto alloc = [&](size_t bytes) {
    char* r = p;
    p += (bytes + 255) & ~(size_t)255;
    return r;
  };
  int* cnt      = (int*)alloc(E_NUM * 4);
  int* offs     = (int*)alloc(E_NUM * 4);
  int* toklist  = (int*)alloc((size_t)E_NUM * T_NUM * 4);
  int* slotE    = (int*)alloc((size_t)T_NUM * TOPK * 4);
  int* slotPos  = (int*)alloc((size_t)T_NUM * TOPK * 4);
  float* wt4    = (float*)alloc((size_t)T_NUM * TOPK * 4);
  float* sigbuf = (float*)alloc((size_t)T_NUM * 4);
  u16* xb  = (u16*)alloc((size_t)T_NUM * H_DIM * 2);
  u16* sgT = (u16*)alloc((size_t)H_DIM * SF_DIM * 2);
  u16* suT = (u16*)alloc((size_t)H_DIM * SF_DIM * 2);
  u16* sdT = (u16*)alloc((size_t)H_DIM * SF_DIM * 2);
  u16* wgT = (u16*)alloc((size_t)E_NUM * H_DIM * F_DIM * 2);
  u16* wuT = (u16*)alloc((size_t)E_NUM * H_DIM * F_DIM * 2);
  u16* wdT = (u16*)alloc((size_t)E_NUM * H_DIM * F_DIM * 2);
  u16* Hs  = (u16*)alloc((size_t)T_NUM * SF_DIM * 2);
  u16* He  = (u16*)alloc((size_t)(P_MAX + 128) * F_DIM * 2);
  float* sharedD = (float*)alloc((size_t)KSPLIT * T_NUM * H_DIM * 4);
  float* Dh      = (float*)alloc((size_t)P_MAX * H_DIM * 4);

  hipMemsetAsync(cnt, 0, E_NUM * 4, stream);
  router_kernel<<<T_NUM, 64, 0, stream>>>(x, gate_w, seg, cnt, toklist,
                                          slotE, slotPos, wt4, sigbuf);
  offs_kernel<<<1, 64, 0, stream>>>(cnt, offs);

  cvt_x<<<(T_NUM * H_DIM / 8) / 256, 256, 0, stream>>>(x, xb);
  transpose_cvt<<<dim3(SF_DIM / 64, H_DIM / 64, 1), 256, 0, stream>>>(sg, sgT, H_DIM, SF_DIM);
  transpose_cvt<<<dim3(SF_DIM / 64, H_DIM / 64, 1), 256, 0, stream>>>(su, suT, H_DIM, SF_DIM);
  transpose_cvt<<<dim3(H_DIM / 64, SF_DIM / 64, 1), 256, 0, stream>>>(sd, sdT, SF_DIM, H_DIM);
  transpose_cvt<<<dim3(F_DIM / 64, H_DIM / 64, E_NUM), 256, 0, stream>>>(wg, wgT, H_DIM, F_DIM);
  transpose_cvt<<<dim3(F_DIM / 64, H_DIM / 64, E_NUM), 256, 0, stream>>>(wu, wuT, H_DIM, F_DIM);
  transpose_cvt<<<dim3(H_DIM / 64, F_DIM / 64, E_NUM), 256, 0, stream>>>(wd, wdT, F_DIM, H_DIM);

  // shared: Hs = silu(xb@sgT)*(xb@suT)   [2048 x 5632]
  gemm_gu<<<dim3(SF_DIM / 64, T_NUM / 128, 1), 256, 0, stream>>>(
      xb, sgT, suT, Hs, H_DIM, SF_DIM, 0, cnt, toklist, offs);
  // experts: He = silu(X_g@wgT)*(X_g@wuT)  [8192 x 768]
  gemm_gu<<<dim3(F_DIM / 64, T_NUM / 128, E_NUM), 256, 0, stream>>>(
      xb, wgT, wuT, He, H_DIM, F_DIM, 1, cnt, toklist, offs);
  // shared down (split-K): sharedD_z = Hs @ sdT chunk z   [2048 x 2048] x4
  gemm_dn_split<<<dim3(H_DIM / 128, T_NUM / 128, KSPLIT), 256, 0, stream>>>(
      Hs, sdT, sharedD, SF_DIM, H_DIM);
  // expert down: Dh = He @ wdT        [8192 x 2048]
  gemm_dn<<<dim3(H_DIM / 128, T_NUM / 128, E_NUM), 256, 0, stream>>>(
      He, wdT, Dh, F_DIM, H_DIM, 1, cnt, offs);

  combine_kernel<<<T_NUM, 256, 0, stream>>>(sharedD, Dh, sigbuf, wt4,
                                            slotE, slotPos, offs, out);
}

// Round 2
// 1198.960 us; speedup vs baseline: 1.0949x; 1.0569x over previous
//
#include <hip/hip_runtime.h>
#include <hip/hip_bf16.h>
#include <math.h>

#define H_DIM 2048
#define F_DIM 768
#define E_NUM 32
#define TOPK 4
#define SF_DIM 5632
#define T_NUM 2048
#define P_MAX (T_NUM * TOPK)
#define KSPLIT 4  // split-K for shared down-proj

// merged-grid block counts
#define NB_GU_SHARED ((SF_DIM / 64) * (T_NUM / 128))            // 88*16 = 1408
#define NB_GU_EXPERT ((F_DIM / 64) * (T_NUM / 128) * E_NUM)     // 12*16*32 = 6144
#define NB_DN_SHARED ((H_DIM / 128) * (T_NUM / 128) * KSPLIT)   // 16*16*4 = 1024
#define NB_DN_EXPERT ((H_DIM / 128) * (T_NUM / 128) * E_NUM)    // 16*16*32 = 8192

typedef __attribute__((ext_vector_type(8))) short short8v;
typedef __attribute__((ext_vector_type(4))) float f4;
typedef unsigned short u16;

__device__ __forceinline__ u16 f2b(float f) {
  unsigned int u = __float_as_uint(f);
  u += 0x7FFFu + ((u >> 16) & 1u);
  return (u16)(u >> 16);
}

__device__ __forceinline__ f4 mfma16(short8v a, short8v b, f4 c) {
  return __builtin_amdgcn_mfma_f32_16x16x32_bf16(a, b, c, 0, 0, 0);
}

// async 16B global->LDS (wave-uniform base + lane*16 ordering)
__device__ __forceinline__ void gld16(const u16* g, u16* l) {
  __builtin_amdgcn_global_load_lds(
      (const __attribute__((address_space(1))) void*)g,
      (__attribute__((address_space(3))) void*)l, 16, 0, 0);
}

// ---------------------------------------------------------------------------
// Router: 1 block (64 threads) per token. fp32 logits/softmax/top-4.
// ---------------------------------------------------------------------------
__global__ __launch_bounds__(64) void router_kernel(
    const float* __restrict__ x, const float* __restrict__ gate_w,
    const float* __restrict__ seg, int* __restrict__ cnt,
    int* __restrict__ toklist, int* __restrict__ slotE,
    int* __restrict__ slotPos, float* __restrict__ wt4,
    float* __restrict__ sigbuf) {
  const int t = blockIdx.x;
  const int l = threadIdx.x;
  const int e = l & 31;
  const int half = l >> 5;
  const float* xr = x + (size_t)t * H_DIM;

  float acc = 0.0f, aseg = 0.0f;
  const int h0 = half * (H_DIM / 2);
  for (int h = 0; h < H_DIM / 2; ++h) {
    float xv = xr[h0 + h];
    acc += xv * gate_w[(h0 + h) * E_NUM + e];
    aseg += xv * seg[h0 + h];
  }
  acc += __shfl_xor(acc, 32, 64);
  aseg += __shfl_xor(aseg, 32, 64);

  float m = acc;
#pragma unroll
  for (int mask = 16; mask >= 1; mask >>= 1) m = fmaxf(m, __shfl_xor(m, mask, 64));
  float p = expf(acc - m);
  float s = p;
#pragma unroll
  for (int mask = 16; mask >= 1; mask >>= 1) s += __shfl_xor(s, mask, 64);
  p /= s;

  float pv = p;
  int ids[TOPK];
  float wv[TOPK];
  float wsum = 0.0f;
#pragma unroll
  for (int k = 0; k < TOPK; ++k) {
    float mv = pv;
    int mi = e;
#pragma unroll
    for (int mask = 16; mask >= 1; mask >>= 1) {
      float ov = __shfl_xor(mv, mask, 64);
      int oi = __shfl_xor(mi, mask, 64);
      if (ov > mv || (ov == mv && oi < mi)) { mv = ov; mi = oi; }
    }
    ids[k] = mi;
    wv[k] = mv;
    wsum += mv;
    if (e == mi) pv = -1.0f;
  }

  if (l < TOPK) {
    int id = ids[l];
    float w = wv[l] / wsum;
    int pos = atomicAdd(&cnt[id], 1);
    toklist[id * T_NUM + pos] = t;
    slotE[t * TOPK + l] = id;
    slotPos[t * TOPK + l] = pos;
    wt4[t * TOPK + l] = w;
  }
  if (l == 0) sigbuf[t] = 1.0f / (1.0f + expf(-aseg));
}

// exclusive prefix over 32 counts
__global__ void offs_kernel(const int* __restrict__ cnt, int* __restrict__ offs) {
  if (threadIdx.x == 0) {
    int s = 0;
    for (int e = 0; e < E_NUM; ++e) { offs[e] = s; s += cnt[e]; }
  }
}

// x fp32 -> bf16 (row-major, no transpose). 8 elems/thread.
__global__ __launch_bounds__(256) void cvt_x(const float* __restrict__ in,
                                             u16* __restrict__ out) {
  int i = blockIdx.x * 256 + threadIdx.x;
  const float4* p = (const float4*)in + (size_t)i * 2;
  float4 a = p[0], b = p[1];
  short8v o;
  o[0] = (short)f2b(a.x); o[1] = (short)f2b(a.y);
  o[2] = (short)f2b(a.z); o[3] = (short)f2b(a.w);
  o[4] = (short)f2b(b.x); o[5] = (short)f2b(b.y);
  o[6] = (short)f2b(b.z); o[7] = (short)f2b(b.w);
  *(short8v*)(out + (size_t)i * 8) = o;
}

// fp32 [R][C] -> bf16 [C][R] (per-z matrix), 64x64 tiles via LDS
__global__ __launch_bounds__(256) void transpose_cvt(
    const float* __restrict__ in, u16* __restrict__ out, int R, int C) {
  in += (size_t)blockIdx.z * R * C;
  out += (size_t)blockIdx.z * R * C;
  const int r0 = blockIdx.y * 64;
  const int c0 = blockIdx.x * 64;
  __shared__ u16 tile[64][72];
  const int tid = threadIdx.x;
  const int tr = tid >> 2, tseg = tid & 3;
  const float* ip = in + (size_t)(r0 + tr) * C + c0 + tseg * 16;
#pragma unroll
  for (int j = 0; j < 4; ++j) {
    float4 v = *(const float4*)(ip + j * 4);
    u16* d = &tile[tr][tseg * 16 + j * 4];
    d[0] = f2b(v.x); d[1] = f2b(v.y); d[2] = f2b(v.z); d[3] = f2b(v.w);
  }
  __syncthreads();
  u16 tmp[16];
#pragma unroll
  for (int j = 0; j < 16; ++j) tmp[j] = tile[tseg * 16 + j][tr];
  u16* op = out + (size_t)(c0 + tr) * R + r0 + tseg * 16;
  *(short8v*)op = *(short8v*)&tmp[0];
  *(short8v*)(op + 8) = *(short8v*)&tmp[8];
}

// ---------------------------------------------------------------------------
// Merged gate+up GEMM (shared + expert paths in ONE grid so both fill the
// machine together; each alone is latency-bound at ~3 blocks/CU).
// H = silu(A@Bg^T)*(A@Bu^T), bf16 out. BM=128, BN=64, BK=32, K=H_DIM.
// bid < NB_GU_SHARED: shared expert (N=SF_DIM, direct rows, out=Hs)
// else: routed expert e (N=F_DIM, gathered rows, out=He)
// ---------------------------------------------------------------------------
__global__ __launch_bounds__(256) void gemm_gu_all(
    const u16* __restrict__ A, const u16* __restrict__ sgT,
    const u16* __restrict__ suT, u16* __restrict__ HsOut,
    const u16* __restrict__ wgT, const u16* __restrict__ wuT,
    u16* __restrict__ HeOut, const int* __restrict__ cnt,
    const int* __restrict__ toklist, const int* __restrict__ offs) {
  const int bid = blockIdx.x;
  const int K = H_DIM;
  const u16 *Bg, *Bu;
  u16* Hout;
  int n0, mtile, count, obase, N, gather, e = 0;
  if (bid < NB_GU_SHARED) {
    mtile = bid / (SF_DIM / 64);
    n0 = (bid % (SF_DIM / 64)) * 64;
    count = 1 << 30; obase = 0; N = SF_DIM; gather = 0;
    Bg = sgT; Bu = suT; Hout = HsOut;
  } else {
    const int r = bid - NB_GU_SHARED;
    e = r / ((F_DIM / 64) * (T_NUM / 128));
    const int rem = r % ((F_DIM / 64) * (T_NUM / 128));
    mtile = rem / (F_DIM / 64);
    n0 = (rem % (F_DIM / 64)) * 64;
    count = cnt[e];
    if (mtile * 128 >= count) return;
    obase = offs[e]; N = F_DIM; gather = 1;
    Bg = wgT + (size_t)e * F_DIM * H_DIM;
    Bu = wuT + (size_t)e * F_DIM * H_DIM;
    Hout = HeOut;
  }

  __shared__ u16 As[128 * 32];
  __shared__ u16 Bgs[64 * 32];
  __shared__ u16 Bus[64 * 32];
  __shared__ int ids[128];

  const int tid = threadIdx.x;
  if (tid < 128) {
    int idx = mtile * 128 + tid;
    ids[tid] = gather ? toklist[e * T_NUM + min(idx, count - 1)] : idx;
  }
  __syncthreads();

  const int s = tid & 3, r0 = tid >> 2;
  const int cA0 = (s + (r0 >> 1)) & 3;
  const int cA1 = (s + ((r0 + 64) >> 1)) & 3;
  const u16* ap0 = A + (size_t)ids[r0] * K + cA0 * 8;
  const u16* ap1 = A + (size_t)ids[r0 + 64] * K + cA1 * 8;
  u16* al0 = As + tid * 8;
  u16* al1 = As + tid * 8 + 2048;
  const u16* bgp = Bg + (size_t)(n0 + r0) * K + cA0 * 8;
  const u16* bup = Bu + (size_t)(n0 + r0) * K + cA0 * 8;
  u16* bgl = Bgs + tid * 8;
  u16* bul = Bus + tid * 8;

  const int lane = tid & 63, w = tid >> 6;
  const int w0 = w & 1, w1 = w >> 1;
  const int ln = lane & 15, q = lane >> 4;

  int aoff[4], boff[2];
#pragma unroll
  for (int mt = 0; mt < 4; ++mt) {
    int r = w0 * 64 + mt * 16 + ln;
    aoff[mt] = r * 32 + ((q - (r >> 1)) & 3) * 8;
  }
#pragma unroll
  for (int nt = 0; nt < 2; ++nt) {
    int r = w1 * 32 + nt * 16 + ln;
    boff[nt] = r * 32 + ((q - (r >> 1)) & 3) * 8;
  }

  const f4 zero = {0.f, 0.f, 0.f, 0.f};
  f4 accg[4][2], accu[4][2];
#pragma unroll
  for (int mt = 0; mt < 4; ++mt)
#pragma unroll
    for (int nt = 0; nt < 2; ++nt) { accg[mt][nt] = zero; accu[mt][nt] = zero; }

  for (int k0 = 0; k0 < K; k0 += 32) {
    gld16(ap0 + k0, al0);
    gld16(ap1 + k0, al1);
    gld16(bgp + k0, bgl);
    gld16(bup + k0, bul);
    __syncthreads();
    short8v av[4], bgv[2], buv[2];
#pragma unroll
    for (int mt = 0; mt < 4; ++mt) av[mt] = *(const short8v*)&As[aoff[mt]];
#pragma unroll
    for (int nt = 0; nt < 2; ++nt) {
      bgv[nt] = *(const short8v*)&Bgs[boff[nt]];
      buv[nt] = *(const short8v*)&Bus[boff[nt]];
    }
#pragma unroll
    for (int mt = 0; mt < 4; ++mt)
#pragma unroll
      for (int nt = 0; nt < 2; ++nt) {
        accg[mt][nt] = mfma16(av[mt], bgv[nt], accg[mt][nt]);
        accu[mt][nt] = mfma16(av[mt], buv[nt], accu[mt][nt]);
      }
    __syncthreads();
  }

#pragma unroll
  for (int mt = 0; mt < 4; ++mt)
#pragma unroll
    for (int nt = 0; nt < 2; ++nt)
#pragma unroll
      for (int r = 0; r < 4; ++r) {
        int m = w0 * 64 + mt * 16 + 4 * q + r;
        int idx = mtile * 128 + m;
        if (idx < count) {
          int n = n0 + w1 * 32 + nt * 16 + ln;
          float g = accg[mt][nt][r], u = accu[mt][nt][r];
          float h = g / (1.0f + __expf(-g)) * u;
          Hout[(size_t)(obase + idx) * N + n] = f2b(h);
        }
      }
}

// ---------------------------------------------------------------------------
// Merged down-proj GEMM (shared split-K + expert paths in ONE grid).
// D = A@Bt^T (fp32 out). BM=128, BN=128, BK=32, N=H_DIM for both paths.
// bid < NB_DN_SHARED: shared down, K=SF_DIM split into KSPLIT chunks,
//   partial sums into sharedD[kz]. else: expert e down, K=F_DIM, out=Dh.
// ---------------------------------------------------------------------------
__global__ __launch_bounds__(256) void gemm_dn_all(
    const u16* __restrict__ HsIn, const u16* __restrict__ sdT,
    float* __restrict__ sharedD, const u16* __restrict__ HeIn,
    const u16* __restrict__ wdT, float* __restrict__ Dh,
    const int* __restrict__ cnt, const int* __restrict__ offs) {
  const int bid = blockIdx.x;
  const u16 *Ap, *Bt;
  float* D;
  int n0, mtile, count, obase, K, kbeg, klen, gather;
  if (bid < NB_DN_SHARED) {
    const int kz = bid / ((H_DIM / 128) * (T_NUM / 128));
    const int rem = bid % ((H_DIM / 128) * (T_NUM / 128));
    mtile = rem / (H_DIM / 128);
    n0 = (rem % (H_DIM / 128)) * 128;
    count = 1 << 30; obase = 0; gather = 0;
    K = SF_DIM; klen = SF_DIM / KSPLIT; kbeg = kz * klen;
    Ap = HsIn; Bt = sdT;
    D = sharedD + (size_t)kz * T_NUM * H_DIM;
  } else {
    const int r = bid - NB_DN_SHARED;
    const int e = r / ((H_DIM / 128) * (T_NUM / 128));
    const int rem = r % ((H_DIM / 128) * (T_NUM / 128));
    mtile = rem / (H_DIM / 128);
    n0 = (rem % (H_DIM / 128)) * 128;
    count = cnt[e];
    if (mtile * 128 >= count) return;
    obase = offs[e]; gather = 1;
    K = F_DIM; klen = F_DIM; kbeg = 0;
    Ap = HeIn; Bt = wdT + (size_t)e * H_DIM * F_DIM;
    D = Dh;
  }

  __shared__ u16 As[128 * 32];
  __shared__ u16 Bs[128 * 32];
  __shared__ int ids[128];

  const int tid = threadIdx.x;
  if (tid < 128) {
    int idx = mtile * 128 + tid;
    ids[tid] = gather ? (obase + min(idx, count - 1)) : idx;
  }
  __syncthreads();

  const int s = tid & 3, r0 = tid >> 2;
  const int cA0 = (s + (r0 >> 1)) & 3;
  const int cA1 = (s + ((r0 + 64) >> 1)) & 3;
  const u16* ap0 = Ap + (size_t)ids[r0] * K + kbeg + cA0 * 8;
  const u16* ap1 = Ap + (size_t)ids[r0 + 64] * K + kbeg + cA1 * 8;
  u16* al0 = As + tid * 8;
  u16* al1 = As + tid * 8 + 2048;
  const u16* bp0 = Bt + (size_t)(n0 + r0) * K + kbeg + cA0 * 8;
  const u16* bp1 = Bt + (size_t)(n0 + r0 + 64) * K + kbeg + cA1 * 8;
  u16* bl0 = Bs + tid * 8;
  u16* bl1 = Bs + tid * 8 + 2048;

  const int lane = tid & 63, w = tid >> 6;
  const int w0 = w & 1, w1 = w >> 1;
  const int ln = lane & 15, q = lane >> 4;

  int aoff[4], boff[4];
#pragma unroll
  for (int mt = 0; mt < 4; ++mt) {
    int r = w0 * 64 + mt * 16 + ln;
    aoff[mt] = r * 32 + ((q - (r >> 1)) & 3) * 8;
    int rb = w1 * 64 + mt * 16 + ln;
    boff[mt] = rb * 32 + ((q - (rb >> 1)) & 3) * 8;
  }

  const f4 zero = {0.f, 0.f, 0.f, 0.f};
  f4 acc[4][4];
#pragma unroll
  for (int mt = 0; mt < 4; ++mt)
#pragma unroll
    for (int nt = 0; nt < 4; ++nt) acc[mt][nt] = zero;

  for (int k0 = 0; k0 < klen; k0 += 32) {
    gld16(ap0 + k0, al0);
    gld16(ap1 + k0, al1);
    gld16(bp0 + k0, bl0);
    gld16(bp1 + k0, bl1);
    __syncthreads();
    short8v av[4], bv[4];
#pragma unroll
    for (int i = 0; i < 4; ++i) {
      av[i] = *(const short8v*)&As[aoff[i]];
      bv[i] = *(const short8v*)&Bs[boff[i]];
    }
#pragma unroll
    for (int mt = 0; mt < 4; ++mt)
#pragma unroll
      for (int nt = 0; nt < 4; ++nt)
        acc[mt][nt] = mfma16(av[mt], bv[nt], acc[mt][nt]);
    __syncthreads();
  }

#pragma unroll
  for (int mt = 0; mt < 4; ++mt)
#pragma unroll
    for (int nt = 0; nt < 4; ++nt)
#pragma unroll
      for (int r = 0; r < 4; ++r) {
        int m = w0 * 64 + mt * 16 + 4 * q + r;
        int idx = mtile * 128 + m;
        if (idx < count) {
          int n = n0 + w1 * 64 + nt * 16 + ln;
          D[(size_t)(obase + idx) * H_DIM + n] = acc[mt][nt][r];
        }
      }
}

// ---------------------------------------------------------------------------
// Final combine: out[t] = sig[t]*sum_z sharedD_z[t] + sum_k wt[t][k]*Dh[slot]
// ---------------------------------------------------------------------------
__global__ __launch_bounds__(256) void combine_kernel(
    const float* __restrict__ sD, const float* __restrict__ Dh,
    const float* __restrict__ sig, const float* __restrict__ wt4,
    const int* __restrict__ slotE, const int* __restrict__ slotPos,
    const int* __restrict__ offs, float* __restrict__ out) {
  const int t = blockIdx.x;
  const int c = threadIdx.x * 8;
  const float sg = sig[t];
  float o[8] = {0.f, 0.f, 0.f, 0.f, 0.f, 0.f, 0.f, 0.f};
#pragma unroll
  for (int z = 0; z < KSPLIT; ++z) {
    const float* sp = sD + ((size_t)z * T_NUM + t) * H_DIM + c;
    float4 a0 = *(const float4*)sp;
    float4 a1 = *(const float4*)(sp + 4);
    o[0] += a0.x; o[1] += a0.y; o[2] += a0.z; o[3] += a0.w;
    o[4] += a1.x; o[5] += a1.y; o[6] += a1.z; o[7] += a1.w;
  }
#pragma unroll
  for (int j = 0; j < 8; ++j) o[j] *= sg;
#pragma unroll
  for (int k = 0; k < TOPK; ++k) {
    int ee = slotE[t * TOPK + k];
    int pp = offs[ee] + slotPos[t * TOPK + k];
    float w = wt4[t * TOPK + k];
    const float* dp = Dh + (size_t)pp * H_DIM + c;
    float4 d0 = *(const float4*)dp;
    float4 d1 = *(const float4*)(dp + 4);
    o[0] += w * d0.x; o[1] += w * d0.y; o[2] += w * d0.z; o[3] += w * d0.w;
    o[4] += w * d1.x; o[5] += w * d1.y; o[6] += w * d1.z; o[7] += w * d1.w;
  }
  float* op = out + (size_t)t * H_DIM + c;
  float4 r0 = {o[0], o[1], o[2], o[3]};
  float4 r1 = {o[4], o[5], o[6], o[7]};
  *(float4*)op = r0;
  *(float4*)(op + 4) = r1;
}

// ---------------------------------------------------------------------------
extern "C" void kernel_launch(void* const* d_in, const int* in_sizes, int n_in,
                              void* d_out, int out_size, void* d_ws, size_t ws_size,
                              hipStream_t stream) {
  const float* x      = (const float*)d_in[0];
  const float* gate_w = (const float*)d_in[1];
  const float* wg     = (const float*)d_in[2];
  const float* wu     = (const float*)d_in[3];
  const float* wd     = (const float*)d_in[4];
  const float* sg     = (const float*)d_in[5];
  const float* su     = (const float*)d_in[6];
  const float* sd     = (const float*)d_in[7];
  const float* seg    = (const float*)d_in[8];
  float* out = (float*)d_out;

  char* p = (char*)d_ws;
  auto alloc = [&](size_t bytes) {
    char* r = p;
    p += (bytes + 255) & ~(size_t)255;
    return r;
  };
  int* cnt      = (int*)alloc(E_NUM * 4);
  int* offs     = (int*)alloc(E_NUM * 4);
  int* toklist  = (int*)alloc((size_t)E_NUM * T_NUM * 4);
  int* slotE    = (int*)alloc((size_t)T_NUM * TOPK * 4);
  int* slotPos  = (int*)alloc((size_t)T_NUM * TOPK * 4);
  float* wt4    = (float*)alloc((size_t)T_NUM * TOPK * 4);
  float* sigbuf = (float*)alloc((size_t)T_NUM * 4);
  u16* xb  = (u16*)alloc((size_t)T_NUM * H_DIM * 2);
  u16* sgT = (u16*)alloc((size_t)H_DIM * SF_DIM * 2);
  u16* suT = (u16*)alloc((size_t)H_DIM * SF_DIM * 2);
  u16* sdT = (u16*)alloc((size_t)H_DIM * SF_DIM * 2);
  u16* wgT = (u16*)alloc((size_t)E_NUM * H_DIM * F_DIM * 2);
  u16* wuT = (u16*)alloc((size_t)E_NUM * H_DIM * F_DIM * 2);
  u16* wdT = (u16*)alloc((size_t)E_NUM * H_DIM * F_DIM * 2);
  u16* Hs  = (u16*)alloc((size_t)T_NUM * SF_DIM * 2);
  u16* He  = (u16*)alloc((size_t)(P_MAX + 128) * F_DIM * 2);
  float* sharedD = (float*)alloc((size_t)KSPLIT * T_NUM * H_DIM * 4);
  float* Dh      = (float*)alloc((size_t)P_MAX * H_DIM * 4);

  hipMemsetAsync(cnt, 0, E_NUM * 4, stream);
  router_kernel<<<T_NUM, 64, 0, stream>>>(x, gate_w, seg, cnt, toklist,
                                          slotE, slotPos, wt4, sigbuf);
  offs_kernel<<<1, 64, 0, stream>>>(cnt, offs);

  cvt_x<<<(T_NUM * H_DIM / 8) / 256, 256, 0, stream>>>(x, xb);
  transpose_cvt<<<dim3(SF_DIM / 64, H_DIM / 64, 1), 256, 0, stream>>>(sg, sgT, H_DIM, SF_DIM);
  transpose_cvt<<<dim3(SF_DIM / 64, H_DIM / 64, 1), 256, 0, stream>>>(su, suT, H_DIM, SF_DIM);
  transpose_cvt<<<dim3(H_DIM / 64, SF_DIM / 64, 1), 256, 0, stream>>>(sd, sdT, SF_DIM, H_DIM);
  transpose_cvt<<<dim3(F_DIM / 64, H_DIM / 64, E_NUM), 256, 0, stream>>>(wg, wgT, H_DIM, F_DIM);
  transpose_cvt<<<dim3(F_DIM / 64, H_DIM / 64, E_NUM), 256, 0, stream>>>(wu, wuT, H_DIM, F_DIM);
  transpose_cvt<<<dim3(H_DIM / 64, F_DIM / 64, E_NUM), 256, 0, stream>>>(wd, wdT, F_DIM, H_DIM);

  // merged gate+up: shared (Hs) + experts (He) in one grid
  gemm_gu_all<<<NB_GU_SHARED + NB_GU_EXPERT, 256, 0, stream>>>(
      xb, sgT, suT, Hs, wgT, wuT, He, cnt, toklist, offs);
  // merged down-proj: shared split-K (sharedD) + experts (Dh) in one grid
  gemm_dn_all<<<NB_DN_SHARED + NB_DN_EXPERT, 256, 0, stream>>>(
      Hs, sdT, sharedD, He, wdT, Dh, cnt, offs);

  combine_kernel<<<T_NUM, 256, 0, stream>>>(sharedD, Dh, sigbuf, wt4,
                                            slotE, slotPos, offs, out);
}